// Round 1
// baseline (397.220 us; speedup 1.0000x reference)
//
#include <hip/hip_runtime.h>
#include <stdint.h>

#define B_ 64
#define D_ 1024
#define O_ 512
#define N_ 128
// rows = O_*D_ = 524288 weight bitstream rows, each of length N_=128

__device__ __forceinline__ uint32_t rotl32(uint32_t x, uint32_t d) {
  return (x << d) | (x >> (32u - d));
}

// Threefry-2x32, 20 rounds, key fixed to jax.random.key(42) -> (0, 42).
__device__ __forceinline__ void threefry2x32(uint32_t c0, uint32_t c1,
                                             uint32_t& r0, uint32_t& r1) {
  const uint32_t ks0 = 0u;
  const uint32_t ks1 = 42u;
  const uint32_t ks2 = 0u ^ 42u ^ 0x1BD11BDAu;
  uint32_t x0 = c0 + ks0;
  uint32_t x1 = c1 + ks1;
#define RND(R) { x0 += x1; x1 = rotl32(x1, R); x1 ^= x0; }
  RND(13) RND(15) RND(26) RND(6)
  x0 += ks1; x1 += ks2 + 1u;
  RND(17) RND(29) RND(16) RND(24)
  x0 += ks2; x1 += ks0 + 2u;
  RND(13) RND(15) RND(26) RND(6)
  x0 += ks0; x1 += ks1 + 3u;
  RND(17) RND(29) RND(16) RND(24)
  x0 += ks1; x1 += ks2 + 4u;
  RND(13) RND(15) RND(26) RND(6)
  x0 += ks2; x1 += ks0 + 5u;
#undef RND
  r0 = x0; r1 = x1;
}

// 32-bit random draw for flat index i, jax_threefry_partitionable semantics:
// counter = (hi32(i)=0, lo32(i)=i), output = out0 ^ out1.
__device__ __forceinline__ uint32_t rand_bits(uint32_t i) {
  uint32_t a, b;
  threefry2x32(0u, i, a, b);
  return a ^ b;
}

// K1: pack input bits along d.  xp[(b*8+g)*128 + t] is a uint4; component e,
// bit j  <->  x[b][d][t] with d = g*128 + e*32 + j.
__global__ void pack_x(const int* __restrict__ x, uint32_t* __restrict__ xp) {
  const int t   = threadIdx.x;            // 0..127
  const int idx = blockIdx.x;             // b*32 + g*4 + e
  const int b   = idx >> 5;
  const int g   = (idx >> 2) & 7;
  const int e   = idx & 3;
  const int* src = x + ((b * D_) + (g * 128 + e * 32)) * N_ + t;
  uint32_t w = 0;
#pragma unroll
  for (int j = 0; j < 32; ++j)
    w |= (uint32_t)(src[j * N_] & 1) << j;
  xp[(((b * 8) + g) * N_ + t) * 4 + e] = w;
}

// K2: per (o,d) row, reproduce the weight bitstream exactly.
// One wave per row: lane holds keys for t=lane and t=lane+64.
// key = (rand_bits>>9)<<7 | t  (monotone in u, stable tie-break by t, distinct).
// The n smallest keys get bit 1.  n = round_half_even(clip(p,0,1)*128).
// Result written t-packed: wtmp[row] = {t0..31, t32..63, t64..95, t96..127}.
__global__ void gen_weights(const float* __restrict__ kern, uint4* __restrict__ wtmp) {
  const int lane = threadIdx.x & 63;
  const int wave = threadIdx.x >> 6;
  const int row0 = blockIdx.x * 32 + wave * 8;
  for (int rr = 0; rr < 8; ++rr) {
    const int row = row0 + rr;
    float p = kern[row];
    p = fminf(fmaxf(p, 0.0f), 1.0f);
    const int n = (int)rintf(p * 128.0f);   // RNE, matches jnp.round

    const uint32_t i0 = (uint32_t)row * 128u + (uint32_t)lane;
    const uint32_t b0 = rand_bits(i0);
    const uint32_t b1 = rand_bits(i0 + 64u);
    const uint32_t k0 = ((b0 >> 9) << 7) | (uint32_t)lane;
    const uint32_t k1 = ((b1 >> 9) << 7) | (uint32_t)(lane + 64);

    uint64_t m0, m1;
    if (n <= 0) {
      m0 = 0ull; m1 = 0ull;
    } else if (n >= 128) {
      m0 = ~0ull; m1 = ~0ull;
    } else {
      // radix-select the n-th smallest 30-bit key via wave ballots
      uint32_t P = 0u;
      int r = n;
      for (int bb = 29; bb >= 0; --bb) {
        const uint32_t pref = P << 1;
        const uint64_t q0 = __ballot((k0 >> bb) == pref);
        const uint64_t q1 = __ballot((k1 >> bb) == pref);
        const int c = __popcll(q0) + __popcll(q1);
        if (r <= c) { P = pref; } else { P = pref + 1u; r -= c; }
      }
      m0 = __ballot(k0 <= P);
      m1 = __ballot(k1 <= P);
    }
    if (lane == 0) {
      wtmp[row] = make_uint4((uint32_t)m0, (uint32_t)(m0 >> 32),
                             (uint32_t)m1, (uint32_t)(m1 >> 32));
    }
  }
}

// K3: transpose t-packed weight rows into d-packed words matching xp layout.
__global__ void pack_w(const uint32_t* __restrict__ wtmp, uint32_t* __restrict__ wp) {
  const int t   = threadIdx.x;            // 0..127
  const int idx = blockIdx.x;             // o*8 + g
  const int o   = idx >> 3;
  const int g   = idx & 7;
  const int word = t >> 5, bit = t & 31;
  const uint32_t* base = wtmp + (size_t)(o * D_ + g * 128) * 4 + word;
#pragma unroll
  for (int e = 0; e < 4; ++e) {
    uint32_t w = 0;
#pragma unroll
    for (int j = 0; j < 32; ++j)
      w |= ((base[(e * 32 + j) * 4] >> bit) & 1u) << j;
    wp[(((o * 8) + g) * N_ + t) * 4 + e] = w;
  }
}

// K4: out[b][o][t] = popc-dot over 1024 d's (32 words) / 128.  Exact ints.
__global__ void popc_gemm(const uint4* __restrict__ wp, const uint4* __restrict__ xp,
                          float* __restrict__ out) {
  const int t     = threadIdx.x & 127;
  const int oi    = threadIdx.x >> 7;
  const int opair = blockIdx.x >> 3;
  const int btile = blockIdx.x & 7;
  const int o     = opair * 2 + oi;

  uint4 w[8];
#pragma unroll
  for (int g = 0; g < 8; ++g) w[g] = wp[(o * 8 + g) * N_ + t];

#pragma unroll
  for (int ib = 0; ib < 8; ++ib) {
    const int b = btile * 8 + ib;
    uint32_t acc = 0;
#pragma unroll
    for (int g = 0; g < 8; ++g) {
      const uint4 xv = xp[(b * 8 + g) * N_ + t];
      acc += __popc(w[g].x & xv.x);
      acc += __popc(w[g].y & xv.y);
      acc += __popc(w[g].z & xv.z);
      acc += __popc(w[g].w & xv.w);
    }
    out[((size_t)(b * O_) + o) * N_ + t] = (float)acc * (1.0f / 128.0f);
  }
}

extern "C" void kernel_launch(void* const* d_in, const int* in_sizes, int n_in,
                              void* d_out, int out_size, void* d_ws, size_t ws_size,
                              hipStream_t stream) {
  const int*   x    = (const int*)d_in[0];     // (64,1024,128) int32 0/1
  const float* kern = (const float*)d_in[1];   // (512,1024) float32
  float*       out  = (float*)d_out;           // (64,512,128) float32

  char* ws = (char*)d_ws;
  uint32_t* xp   = (uint32_t*)ws;                    // 1 MB
  uint4*    wtmp = (uint4*)(ws + (1u << 20));        // 8 MB
  uint32_t* wp   = (uint32_t*)(ws + (9u << 20));     // 8 MB

  hipLaunchKernelGGL(pack_x,      dim3(2048),  dim3(128), 0, stream, x, xp);
  hipLaunchKernelGGL(gen_weights, dim3(16384), dim3(256), 0, stream, kern, wtmp);
  hipLaunchKernelGGL(pack_w,      dim3(4096),  dim3(128), 0, stream,
                     (const uint32_t*)wtmp, wp);
  hipLaunchKernelGGL(popc_gemm,   dim3(2048),  dim3(256), 0, stream,
                     (const uint4*)wp, (const uint4*)xp, out);
}

// Round 2
// 263.112 us; speedup vs baseline: 1.5097x; 1.5097x over previous
//
#include <hip/hip_runtime.h>
#include <stdint.h>

#define B_ 64
#define D_ 1024
#define O_ 512
#define N_ 128
// rows = O_*D_ = 524288 weight bitstream rows, each of length N_=128

__device__ __forceinline__ uint32_t rotl32(uint32_t x, uint32_t d) {
  return (x << d) | (x >> (32u - d));
}

// Threefry-2x32, 20 rounds, key fixed to jax.random.key(42) -> (0, 42).
__device__ __forceinline__ void threefry2x32(uint32_t c0, uint32_t c1,
                                             uint32_t& r0, uint32_t& r1) {
  const uint32_t ks0 = 0u;
  const uint32_t ks1 = 42u;
  const uint32_t ks2 = 0u ^ 42u ^ 0x1BD11BDAu;
  uint32_t x0 = c0 + ks0;
  uint32_t x1 = c1 + ks1;
#define RND(R) { x0 += x1; x1 = rotl32(x1, R); x1 ^= x0; }
  RND(13) RND(15) RND(26) RND(6)
  x0 += ks1; x1 += ks2 + 1u;
  RND(17) RND(29) RND(16) RND(24)
  x0 += ks2; x1 += ks0 + 2u;
  RND(13) RND(15) RND(26) RND(6)
  x0 += ks0; x1 += ks1 + 3u;
  RND(17) RND(29) RND(16) RND(24)
  x0 += ks1; x1 += ks2 + 4u;
  RND(13) RND(15) RND(26) RND(6)
  x0 += ks2; x1 += ks0 + 5u;
#undef RND
  r0 = x0; r1 = x1;
}

// 32-bit random draw for flat index i, jax_threefry_partitionable semantics:
// counter = (hi32(i)=0, lo32(i)=i), output = out0 ^ out1.
__device__ __forceinline__ uint32_t rand_bits(uint32_t i) {
  uint32_t a, b;
  threefry2x32(0u, i, a, b);
  return a ^ b;
}

// K1: pack input bits along d.  xp[(b*8+g)*128 + t] is a uint4; component e,
// bit j  <->  x[b][d][t] with d = g*128 + e*32 + j.
__global__ void pack_x(const int* __restrict__ x, uint32_t* __restrict__ xp) {
  const int t   = threadIdx.x;            // 0..127
  const int idx = blockIdx.x;             // b*32 + g*4 + e
  const int b   = idx >> 5;
  const int g   = (idx >> 2) & 7;
  const int e   = idx & 3;
  const int* src = x + ((b * D_) + (g * 128 + e * 32)) * N_ + t;
  uint32_t w = 0;
#pragma unroll
  for (int j = 0; j < 32; ++j)
    w |= (uint32_t)(src[j * N_] & 1) << j;
  xp[(((b * 8) + g) * N_ + t) * 4 + e] = w;
}

// K2: per (o,d) row, reproduce the weight bitstream exactly.
// One wave per row: lane holds keys for t=lane and t=lane+64.
// key = (rand_bits>>9)<<7 | t  (monotone in u, stable tie-break by t, distinct).
// The n smallest keys get bit 1.  n = round_half_even(clip(p,0,1)*128).
//
// Early-exit radix select: all 128 keys are distinct, so as soon as the
// candidate set inside the current prefix P (at bit position bb) has size 1,
// that unique key IS the n-th smallest.  The output mask then needs no key
// extraction: keys < n-th have (k>>bb) < P, and the n-th is the unique key
// with (k>>bb) == P, so  mask = ((k >> bb) <= P).  Expected ~9 iterations
// instead of the fixed 30.
__global__ void gen_weights(const float* __restrict__ kern, uint4* __restrict__ wtmp) {
  const int lane = threadIdx.x & 63;
  const int wave = threadIdx.x >> 6;
  const int row0 = blockIdx.x * 32 + wave * 8;
  for (int rr = 0; rr < 8; ++rr) {
    const int row = row0 + rr;
    float p = kern[row];
    p = fminf(fmaxf(p, 0.0f), 1.0f);
    const int n = (int)rintf(p * 128.0f);   // RNE, matches jnp.round

    const uint32_t i0 = (uint32_t)row * 128u + (uint32_t)lane;
    const uint32_t b0 = rand_bits(i0);
    const uint32_t b1 = rand_bits(i0 + 64u);
    const uint32_t k0 = ((b0 >> 9) << 7) | (uint32_t)lane;
    const uint32_t k1 = ((b1 >> 9) << 7) | (uint32_t)(lane + 64);

    uint64_t m0, m1;
    if (n <= 0) {
      m0 = 0ull; m1 = 0ull;
    } else if (n >= 128) {
      m0 = ~0ull; m1 = ~0ull;
    } else {
      uint32_t P = 0u;
      int r = n;          // 1-based rank of target within candidate set
      int sz = 128;       // candidate-set size
      int bb = 29;
      while (true) {
        const uint32_t pref = P << 1;
        const uint64_t q0 = __ballot((k0 >> bb) == pref);
        const uint64_t q1 = __ballot((k1 >> bb) == pref);
        const int c = __popcll(q0) + __popcll(q1);
        const bool zero = (r <= c);
        P  = zero ? pref : (pref + 1u);
        r  = zero ? r : (r - c);
        sz = zero ? c : (sz - c);
        if (sz == 1 || bb == 0) break;
        --bb;
      }
      m0 = __ballot((k0 >> bb) <= P);
      m1 = __ballot((k1 >> bb) <= P);
    }
    if (lane == 0) {
      wtmp[row] = make_uint4((uint32_t)m0, (uint32_t)(m0 >> 32),
                             (uint32_t)m1, (uint32_t)(m1 >> 32));
    }
  }
}

// K3: transpose t-packed weight rows into d-packed words matching xp layout.
__global__ void pack_w(const uint32_t* __restrict__ wtmp, uint32_t* __restrict__ wp) {
  const int t   = threadIdx.x;            // 0..127
  const int idx = blockIdx.x;             // o*8 + g
  const int o   = idx >> 3;
  const int g   = idx & 7;
  const int word = t >> 5, bit = t & 31;
  const uint32_t* base = wtmp + (size_t)(o * D_ + g * 128) * 4 + word;
#pragma unroll
  for (int e = 0; e < 4; ++e) {
    uint32_t w = 0;
#pragma unroll
    for (int j = 0; j < 32; ++j)
      w |= ((base[(e * 32 + j) * 4] >> bit) & 1u) << j;
    wp[(((o * 8) + g) * N_ + t) * 4 + e] = w;
  }
}

// K4: out[b][o][t] = popc-dot over 1024 d's (32 words) / 128.  Exact ints.
__global__ void popc_gemm(const uint4* __restrict__ wp, const uint4* __restrict__ xp,
                          float* __restrict__ out) {
  const int t     = threadIdx.x & 127;
  const int oi    = threadIdx.x >> 7;
  const int opair = blockIdx.x >> 3;
  const int btile = blockIdx.x & 7;
  const int o     = opair * 2 + oi;

  uint4 w[8];
#pragma unroll
  for (int g = 0; g < 8; ++g) w[g] = wp[(o * 8 + g) * N_ + t];

#pragma unroll
  for (int ib = 0; ib < 8; ++ib) {
    const int b = btile * 8 + ib;
    uint32_t acc = 0;
#pragma unroll
    for (int g = 0; g < 8; ++g) {
      const uint4 xv = xp[(b * 8 + g) * N_ + t];
      acc += __popc(w[g].x & xv.x);
      acc += __popc(w[g].y & xv.y);
      acc += __popc(w[g].z & xv.z);
      acc += __popc(w[g].w & xv.w);
    }
    out[((size_t)(b * O_) + o) * N_ + t] = (float)acc * (1.0f / 128.0f);
  }
}

extern "C" void kernel_launch(void* const* d_in, const int* in_sizes, int n_in,
                              void* d_out, int out_size, void* d_ws, size_t ws_size,
                              hipStream_t stream) {
  const int*   x    = (const int*)d_in[0];     // (64,1024,128) int32 0/1
  const float* kern = (const float*)d_in[1];   // (512,1024) float32
  float*       out  = (float*)d_out;           // (64,512,128) float32

  char* ws = (char*)d_ws;
  uint32_t* xp   = (uint32_t*)ws;                    // 1 MB
  uint4*    wtmp = (uint4*)(ws + (1u << 20));        // 8 MB
  uint32_t* wp   = (uint32_t*)(ws + (9u << 20));     // 8 MB

  hipLaunchKernelGGL(pack_x,      dim3(2048),  dim3(128), 0, stream, x, xp);
  hipLaunchKernelGGL(gen_weights, dim3(16384), dim3(256), 0, stream, kern, wtmp);
  hipLaunchKernelGGL(pack_w,      dim3(4096),  dim3(128), 0, stream,
                     (const uint32_t*)wtmp, wp);
  hipLaunchKernelGGL(popc_gemm,   dim3(2048),  dim3(256), 0, stream,
                     (const uint4*)wp, (const uint4*)xp, out);
}

// Round 4
// 236.144 us; speedup vs baseline: 1.6821x; 1.1142x over previous
//
#include <hip/hip_runtime.h>
#include <stdint.h>

#define B_ 64
#define D_ 1024
#define O_ 512
#define N_ 128
// rows = O_*D_ = 524288 weight bitstream rows, each of length N_=128

__device__ __forceinline__ uint32_t rotl32(uint32_t x, uint32_t d) {
  // v_alignbit_b32: ((x:x) >> (32-d)) == rotl(x, d) — single VALU inst.
  return __builtin_amdgcn_alignbit(x, x, 32u - d);
}

// Threefry-2x32, 20 rounds, key fixed to jax.random.key(42) -> (0, 42).
__device__ __forceinline__ void threefry2x32(uint32_t c0, uint32_t c1,
                                             uint32_t& r0, uint32_t& r1) {
  const uint32_t ks0 = 0u;
  const uint32_t ks1 = 42u;
  const uint32_t ks2 = 0u ^ 42u ^ 0x1BD11BDAu;
  uint32_t x0 = c0 + ks0;
  uint32_t x1 = c1 + ks1;
#define RND(R) { x0 += x1; x1 = rotl32(x1, R); x1 ^= x0; }
  RND(13) RND(15) RND(26) RND(6)
  x0 += ks1; x1 += ks2 + 1u;
  RND(17) RND(29) RND(16) RND(24)
  x0 += ks2; x1 += ks0 + 2u;
  RND(13) RND(15) RND(26) RND(6)
  x0 += ks0; x1 += ks1 + 3u;
  RND(17) RND(29) RND(16) RND(24)
  x0 += ks1; x1 += ks2 + 4u;
  RND(13) RND(15) RND(26) RND(6)
  x0 += ks2; x1 += ks0 + 5u;
#undef RND
  r0 = x0; r1 = x1;
}

// 32-bit random draw for flat index i, jax_threefry_partitionable semantics:
// counter = (hi32(i)=0, lo32(i)=i), output = out0 ^ out1.
__device__ __forceinline__ uint32_t rand_bits(uint32_t i) {
  uint32_t a, b;
  threefry2x32(0u, i, a, b);
  return a ^ b;
}

// K1: pack input bits along d.  xp[(b*8+g)*128 + t] is a uint4; component e,
// bit j  <->  x[b][d][t] with d = g*128 + e*32 + j.
__global__ void pack_x(const int* __restrict__ x, uint32_t* __restrict__ xp) {
  const int t   = threadIdx.x;            // 0..127
  const int idx = blockIdx.x;             // b*32 + g*4 + e
  const int b   = idx >> 5;
  const int g   = (idx >> 2) & 7;
  const int e   = idx & 3;
  const int* src = x + ((b * D_) + (g * 128 + e * 32)) * N_ + t;
  uint32_t w = 0;
#pragma unroll
  for (int j = 0; j < 32; ++j)
    w |= (uint32_t)(src[j * N_] & 1) << j;
  xp[(((b * 8) + g) * N_ + t) * 4 + e] = w;
}

// K2: per (o,d) row, reproduce the weight bitstream exactly.
// One wave per row: lane holds keys for t=lane and t=lane+64.
// key = (rand_bits>>9)<<7 | t  (monotone in u, stable tie-break by t, distinct).
// The n smallest keys get bit 1.  n = round_half_even(clip(p,0,1)*128).
//
// Early-exit radix select with SCALARIZED state: n is wave-uniform, so after
// readfirstlane the whole select state machine (P, r, sz, bb) lives in SGPRs.
// Per-iter VALU is exactly 4 insts (2 shifts + 2 ballot-cmps); the bookkeeping
// (s_bcnt1/s_add/s_cselect/s_cbranch) runs on the scalar pipe in parallel.
__global__ void gen_weights(const float* __restrict__ kern, uint4* __restrict__ wtmp) {
  const int lane = threadIdx.x & 63;
  const int wave = threadIdx.x >> 6;
  const int row0 = blockIdx.x * 32 + wave * 8;
#pragma unroll
  for (int rr = 0; rr < 8; ++rr) {
    const int row = row0 + rr;
    float p = kern[row];
    p = fminf(fmaxf(p, 0.0f), 1.0f);
    const int n = __builtin_amdgcn_readfirstlane((int)rintf(p * 128.0f)); // RNE; uniform -> SGPR

    const uint32_t i0 = (uint32_t)row * 128u + (uint32_t)lane;
    const uint32_t b0 = rand_bits(i0);
    const uint32_t b1 = rand_bits(i0 + 64u);
    const uint32_t k0 = ((b0 >> 9) << 7) | (uint32_t)lane;
    const uint32_t k1 = ((b1 >> 9) << 7) | (uint32_t)(lane + 64);

    uint64_t m0, m1;
    if (n <= 0) {                 // scalar branch (s_cmp/s_cbranch)
      m0 = 0ull; m1 = 0ull;
    } else if (n >= 128) {
      m0 = ~0ull; m1 = ~0ull;
    } else {
      uint32_t P = 0u;            // SGPR
      int r = n;                  // SGPR: 1-based rank within candidate set
      int sz = 128;               // SGPR: candidate-set size
      int bb = 29;                // SGPR
      while (true) {
        const uint32_t pref = P << 1;                       // s_lshl
        const uint64_t q0 = __ballot((k0 >> bb) == pref);   // v_lshr + v_cmp
        const uint64_t q1 = __ballot((k1 >> bb) == pref);   // v_lshr + v_cmp
        const int c = __popcll(q0) + __popcll(q1);          // s_bcnt1 x2 + s_add
        const bool zero = (r <= c);                         // s_cmp
        P  = zero ? pref : (pref + 1u);                     // s_cselect
        r  = zero ? r : (r - c);
        sz = zero ? c : (sz - c);
        if (sz == 1 || bb == 0) break;                      // s_cmp + s_cbranch
        --bb;
      }
      m0 = __ballot((k0 >> bb) <= P);
      m1 = __ballot((k1 >> bb) <= P);
    }
    if (lane == 0) {
      wtmp[row] = make_uint4((uint32_t)m0, (uint32_t)(m0 >> 32),
                             (uint32_t)m1, (uint32_t)(m1 >> 32));
    }
  }
}

// K3: transpose t-packed weight rows into d-packed words matching xp layout.
__global__ void pack_w(const uint32_t* __restrict__ wtmp, uint32_t* __restrict__ wp) {
  const int t   = threadIdx.x;            // 0..127
  const int idx = blockIdx.x;             // o*8 + g
  const int o   = idx >> 3;
  const int g   = idx & 7;
  const int word = t >> 5, bit = t & 31;
  const uint32_t* base = wtmp + (size_t)(o * D_ + g * 128) * 4 + word;
#pragma unroll
  for (int e = 0; e < 4; ++e) {
    uint32_t w = 0;
#pragma unroll
    for (int j = 0; j < 32; ++j)
      w |= ((base[(e * 32 + j) * 4] >> bit) & 1u) << j;
    wp[(((o * 8) + g) * N_ + t) * 4 + e] = w;
  }
}

// K4: out[b][o][t] = popc-dot over 1024 d's (32 words) / 128.  Exact ints.
__global__ void popc_gemm(const uint4* __restrict__ wp, const uint4* __restrict__ xp,
                          float* __restrict__ out) {
  const int t     = threadIdx.x & 127;
  const int oi    = threadIdx.x >> 7;
  const int opair = blockIdx.x >> 3;
  const int btile = blockIdx.x & 7;
  const int o     = opair * 2 + oi;

  uint4 w[8];
#pragma unroll
  for (int g = 0; g < 8; ++g) w[g] = wp[(o * 8 + g) * N_ + t];

#pragma unroll
  for (int ib = 0; ib < 8; ++ib) {
    const int b = btile * 8 + ib;
    uint32_t acc = 0;
#pragma unroll
    for (int g = 0; g < 8; ++g) {
      const uint4 xv = xp[(b * 8 + g) * N_ + t];
      acc += __popc(w[g].x & xv.x);
      acc += __popc(w[g].y & xv.y);
      acc += __popc(w[g].z & xv.z);
      acc += __popc(w[g].w & xv.w);
    }
    out[((size_t)(b * O_) + o) * N_ + t] = (float)acc * (1.0f / 128.0f);
  }
}

extern "C" void kernel_launch(void* const* d_in, const int* in_sizes, int n_in,
                              void* d_out, int out_size, void* d_ws, size_t ws_size,
                              hipStream_t stream) {
  const int*   x    = (const int*)d_in[0];     // (64,1024,128) int32 0/1
  const float* kern = (const float*)d_in[1];   // (512,1024) float32
  float*       out  = (float*)d_out;           // (64,512,128) float32

  char* ws = (char*)d_ws;
  uint32_t* xp   = (uint32_t*)ws;                    // 1 MB
  uint4*    wtmp = (uint4*)(ws + (1u << 20));        // 8 MB
  uint32_t* wp   = (uint32_t*)(ws + (9u << 20));     // 8 MB

  hipLaunchKernelGGL(pack_x,      dim3(2048),  dim3(128), 0, stream, x, xp);
  hipLaunchKernelGGL(gen_weights, dim3(16384), dim3(256), 0, stream, kern, wtmp);
  hipLaunchKernelGGL(pack_w,      dim3(4096),  dim3(128), 0, stream,
                     (const uint32_t*)wtmp, wp);
  hipLaunchKernelGGL(popc_gemm,   dim3(2048),  dim3(256), 0, stream,
                     (const uint4*)wp, (const uint4*)xp, out);
}

// Round 7
// 193.529 us; speedup vs baseline: 2.0525x; 1.2202x over previous
//
#include <hip/hip_runtime.h>
#include <stdint.h>

#define B_ 64
#define D_ 1024
#define O_ 512
#define N_ 128
// rows = O_*D_ = 524288 weight bitstream rows, each of length N_=128

__device__ __forceinline__ uint32_t rotl32(uint32_t x, uint32_t d) {
  // v_alignbit_b32: ((x:x) >> (32-d)) == rotl(x, d) — single VALU inst.
  return __builtin_amdgcn_alignbit(x, x, 32u - d);
}

// Threefry-2x32, 20 rounds, key fixed to jax.random.key(42) -> (0, 42).
__device__ __forceinline__ void threefry2x32(uint32_t c0, uint32_t c1,
                                             uint32_t& r0, uint32_t& r1) {
  const uint32_t ks0 = 0u;
  const uint32_t ks1 = 42u;
  const uint32_t ks2 = 0u ^ 42u ^ 0x1BD11BDAu;
  uint32_t x0 = c0 + ks0;
  uint32_t x1 = c1 + ks1;
#define RND(R) { x0 += x1; x1 = rotl32(x1, R); x1 ^= x0; }
  RND(13) RND(15) RND(26) RND(6)
  x0 += ks1; x1 += ks2 + 1u;
  RND(17) RND(29) RND(16) RND(24)
  x0 += ks2; x1 += ks0 + 2u;
  RND(13) RND(15) RND(26) RND(6)
  x0 += ks0; x1 += ks1 + 3u;
  RND(17) RND(29) RND(16) RND(24)
  x0 += ks1; x1 += ks2 + 4u;
  RND(13) RND(15) RND(26) RND(6)
  x0 += ks2; x1 += ks0 + 5u;
#undef RND
  r0 = x0; r1 = x1;
}

// 32-bit random draw for flat index i, jax_threefry_partitionable semantics:
// counter = (hi32(i)=0, lo32(i)=i), output = out0 ^ out1.
__device__ __forceinline__ uint32_t rand_bits(uint32_t i) {
  uint32_t a, b;
  threefry2x32(0u, i, a, b);
  return a ^ b;
}

// K1: pack input bits along d.  xp[(b*8+g)*128 + t] is a uint4; component e,
// bit j  <->  x[b][d][t] with d = g*128 + e*32 + j.
__global__ void pack_x(const int* __restrict__ x, uint32_t* __restrict__ xp) {
  const int t   = threadIdx.x;            // 0..127
  const int idx = blockIdx.x;             // b*32 + g*4 + e
  const int b   = idx >> 5;
  const int g   = (idx >> 2) & 7;
  const int e   = idx & 3;
  const int* src = x + ((b * D_) + (g * 128 + e * 32)) * N_ + t;
  uint32_t w = 0;
#pragma unroll
  for (int j = 0; j < 32; ++j)
    w |= (uint32_t)(src[j * N_] & 1) << j;
  xp[(((b * 8) + g) * N_ + t) * 4 + e] = w;
}

// K2: per (o,d) row, reproduce the weight bitstream exactly.
// One wave per row: lane holds keys for t=lane and t=lane+64.
// key = (rand>>9)<<7 | t == ((rand>>2)&0xFFFFFF80) | t  (monotone in u,
// stable tie-break by t, all 128 keys distinct).
// The n smallest keys get bit 1.  n = round_half_even(clip(p,0,1)*128).
//
// Selection = binary search on key VALUE, state machine entirely in SGPRs
// via inline asm.  Invariant: #(k < lo) < n <= #(k < hi).  Exit when
// cnt == n: the two ballots of (k < mid) ARE the output mask (the n
// smallest keys).  Distinct keys guarantee exit before the interval
// collapses.  Per iter: 2 VALU + ~9 SALU (scalar pipe runs in parallel).
// n enters the asm as a VGPR and is scalarized with an explicit
// v_readfirstlane_b32 (LLVM doesn't honor "s" constraints on VGPR-derived
// values — Round-5 compile failure).
__global__ void gen_weights(const float* __restrict__ kern, uint4* __restrict__ wtmp) {
  const int lane = threadIdx.x & 63;
  const int wave = threadIdx.x >> 6;
  const int row0 = blockIdx.x * 32 + wave * 8;
  const uint32_t lane2 = (uint32_t)lane + 64u;
  const uint32_t KMASK = 0xFFFFFF80u;
#pragma unroll
  for (int rr = 0; rr < 8; ++rr) {
    const int row = row0 + rr;
    float p = kern[row];
    p = fminf(fmaxf(p, 0.0f), 1.0f);
    const int n = (int)rintf(p * 128.0f);   // RNE, matches jnp.round; uniform

    const uint32_t i0 = (uint32_t)row * 128u + (uint32_t)lane;
    const uint32_t b0 = rand_bits(i0);
    const uint32_t b1 = rand_bits(i0 + 64u);
    const uint32_t k0 = ((b0 >> 2) & KMASK) | (uint32_t)lane;
    const uint32_t k1 = ((b1 >> 2) & KMASK) | lane2;

    uint64_t m0, m1;
    if (n <= 0) {                 // uniform condition
      m0 = 0ull; m1 = 0ull;
    } else if (n >= 128) {
      m0 = ~0ull; m1 = ~0ull;
    } else {
      uint64_t q0, q1;
      uint32_t lo, hi, mid, c, c2, ns;
      asm volatile(
        "v_readfirstlane_b32 %[ns], %[nv]\n\t"   // n -> SGPR, guaranteed
        "s_mov_b32 %[lo], 0\n\t"
        "s_mov_b32 %[hi], 0x40000000\n\t"        // 2^30 (keys are 30-bit)
        "Lbs%=:\n\t"
        "s_add_u32 %[mid], %[lo], %[hi]\n\t"
        "s_lshr_b32 %[mid], %[mid], 1\n\t"
        "v_cmp_lt_u32 %[q0], %[k0], %[mid]\n\t"  // ballot stream 0
        "v_cmp_lt_u32 %[q1], %[k1], %[mid]\n\t"  // ballot stream 1
        "s_bcnt1_i32_b64 %[c], %[q0]\n\t"
        "s_bcnt1_i32_b64 %[c2], %[q1]\n\t"
        "s_add_i32 %[c], %[c], %[c2]\n\t"
        "s_cmp_ge_i32 %[c], %[ns]\n\t"
        "s_cselect_b32 %[hi], %[mid], %[hi]\n\t" // cnt>=n ? hi=mid : lo=mid
        "s_cselect_b32 %[lo], %[lo], %[mid]\n\t"
        "s_cmp_lg_i32 %[c], %[ns]\n\t"
        "s_cbranch_scc1 Lbs%=\n\t"
        : [q0] "=&s"(q0), [q1] "=&s"(q1), [lo] "=&s"(lo), [hi] "=&s"(hi),
          [mid] "=&s"(mid), [c] "=&s"(c), [c2] "=&s"(c2), [ns] "=&s"(ns)
        : [k0] "v"(k0), [k1] "v"(k1), [nv] "v"(n)
        : "scc");
      m0 = q0; m1 = q1;
    }
    if (lane == 0) {
      wtmp[row] = make_uint4((uint32_t)m0, (uint32_t)(m0 >> 32),
                             (uint32_t)m1, (uint32_t)(m1 >> 32));
    }
  }
}

// K3: transpose t-packed weight rows into d-packed words matching xp layout.
__global__ void pack_w(const uint32_t* __restrict__ wtmp, uint32_t* __restrict__ wp) {
  const int t   = threadIdx.x;            // 0..127
  const int idx = blockIdx.x;             // o*8 + g
  const int o   = idx >> 3;
  const int g   = idx & 7;
  const int word = t >> 5, bit = t & 31;
  const uint32_t* base = wtmp + (size_t)(o * D_ + g * 128) * 4 + word;
#pragma unroll
  for (int e = 0; e < 4; ++e) {
    uint32_t w = 0;
#pragma unroll
    for (int j = 0; j < 32; ++j)
      w |= ((base[(e * 32 + j) * 4] >> bit) & 1u) << j;
    wp[(((o * 8) + g) * N_ + t) * 4 + e] = w;
  }
}

// K4: out[b][o][t] = popc-dot over 1024 d's (32 words) / 128.  Exact ints.
__global__ void popc_gemm(const uint4* __restrict__ wp, const uint4* __restrict__ xp,
                          float* __restrict__ out) {
  const int t     = threadIdx.x & 127;
  const int oi    = threadIdx.x >> 7;
  const int opair = blockIdx.x >> 3;
  const int btile = blockIdx.x & 7;
  const int o     = opair * 2 + oi;

  uint4 w[8];
#pragma unroll
  for (int g = 0; g < 8; ++g) w[g] = wp[(o * 8 + g) * N_ + t];

#pragma unroll
  for (int ib = 0; ib < 8; ++ib) {
    const int b = btile * 8 + ib;
    uint32_t acc = 0;
#pragma unroll
    for (int g = 0; g < 8; ++g) {
      const uint4 xv = xp[(b * 8 + g) * N_ + t];
      acc += __popc(w[g].x & xv.x);
      acc += __popc(w[g].y & xv.y);
      acc += __popc(w[g].z & xv.z);
      acc += __popc(w[g].w & xv.w);
    }
    out[((size_t)(b * O_) + o) * N_ + t] = (float)acc * (1.0f / 128.0f);
  }
}

extern "C" void kernel_launch(void* const* d_in, const int* in_sizes, int n_in,
                              void* d_out, int out_size, void* d_ws, size_t ws_size,
                              hipStream_t stream) {
  const int*   x    = (const int*)d_in[0];     // (64,1024,128) int32 0/1
  const float* kern = (const float*)d_in[1];   // (512,1024) float32
  float*       out  = (float*)d_out;           // (64,512,128) float32

  char* ws = (char*)d_ws;
  uint32_t* xp   = (uint32_t*)ws;                    // 1 MB
  uint4*    wtmp = (uint4*)(ws + (1u << 20));        // 8 MB
  uint32_t* wp   = (uint32_t*)(ws + (9u << 20));     // 8 MB

  hipLaunchKernelGGL(pack_x,      dim3(2048),  dim3(128), 0, stream, x, xp);
  hipLaunchKernelGGL(gen_weights, dim3(16384), dim3(256), 0, stream, kern, wtmp);
  hipLaunchKernelGGL(pack_w,      dim3(4096),  dim3(128), 0, stream,
                     (const uint32_t*)wtmp, wp);
  hipLaunchKernelGGL(popc_gemm,   dim3(2048),  dim3(256), 0, stream,
                     (const uint4*)wp, (const uint4*)xp, out);
}